// Round 15
// baseline (691.376 us; speedup 1.0000x reference)
//
#include <hip/hip_runtime.h>
#include <math.h>

#define N_NODES 100000
#define NEDGE 64
#define NFEAT 11
#define EFEAT 30
#define MEM 64
#define MSGIN 174
#define ROWS_PB 1024
#define NB_BULK 98           // ceil(100000/1024)
#define NSLOT 128
#define WF_MAGIC 0x7E000000
#define GRID_ALL (1 + NB_BULK)

// ws layout (bytes)
#define WS_PART_OFF  0
#define WS_WFLAG_OFF ((size_t)NB_BULK*12*sizeof(double))   // 9408, 8-aligned

// smem float offsets (single overlaid buffer; bulk blocks reuse [0,11264) as tile)
#define OFF_H    0        // sH [128][64] = 8192
#define OFF_SLAB 8192     // 4096 f: per-tick sX[16][256]; readout scratch after ticks
#define OFF_NF   12288    // sNF [128][12] = 1536   (bulk: sG/sCl/sW here)
#define OFF_WNP  13824    // sWnp [11][64] = 704
#define OFF_BIH  14528    // 192
#define OFF_BHH  14720    // 192
#define OFF_BMSG 14912    // 64
#define OFF_WG   14976    // 64
#define OFF_BNP  15040    // 64
#define OFF_INT  15104    // ints: sEp 128 | sMap 128 | sDef 64 | sAny 1
#define SMEM_F   15488    // 61952 B < 64 KB

__device__ __forceinline__ float sigmoidf_(float x) { return 1.f/(1.f+expf(-x)); }

// ---- one edge, one wave: 4 phases, 4 block barriers (uniform call sites) ----
__device__ __forceinline__ void edge_phases(
    int e, bool act, int w, int lane,
    float* sHf, float* slab, const int* sMap,
    const float* sBIH, const float* sBHH, const float* sBMSG,
    const float* __restrict__ Wmsg, const float* __restrict__ Wih, const float* __restrict__ Whh,
    const float* __restrict__ ef, const float* __restrict__ ts,
    const float* __restrict__ w0, const float* __restrict__ b0,
    const float* __restrict__ tW, const float* __restrict__ tB)
{
  int ss = sMap[e], dd = sMap[64+e];
  float* X = slab + w*256;
  // A: build X = [h_s | h_d | ef | te]
  if (act) {
    X[lane]      = sHf[ss*64 + lane];
    X[64 + lane] = sHf[dd*64 + lane];
    if (lane < EFEAT) X[128 + lane] = ef[e*EFEAT + lane];
    if (lane < 16) {
      float tt = ts[e];
      X[158 + lane] = (lane == 0) ? (tt*w0[0] + b0[0]) : sinf(tt*tW[lane-1] + tB[lane-1]);
    }
  }
  __syncthreads();
  // B: msg = relu(Wmsg^T X + b)  (lane -> output col)
  if (act) {
    float a0=0.f,a1=0.f,a2=0.f,a3=0.f;
    #pragma unroll
    for (int k = 0; k < 172; k += 4) {
      a0 += Wmsg[(k  )*MEM + lane]*X[k  ];
      a1 += Wmsg[(k+1)*MEM + lane]*X[k+1];
      a2 += Wmsg[(k+2)*MEM + lane]*X[k+2];
      a3 += Wmsg[(k+3)*MEM + lane]*X[k+3];
    }
    a0 += Wmsg[172*MEM + lane]*X[172];
    a1 += Wmsg[173*MEM + lane]*X[173];
    X[192 + lane] = fmaxf((a0+a1)+(a2+a3) + sBMSG[lane], 0.f);
  }
  __syncthreads();
  // C: gates (lane owns rows lane, 64+lane, 128+lane) + GRU update
  float gi0=0.f, gi1=0.f, gi2=0.f;
  bool same = (ss == dd);
  if (act) {
    gi0 = sBIH[lane]; gi1 = sBIH[64+lane]; gi2 = sBIH[128+lane];
    float s0 = sBHH[lane], s1 = sBHH[64+lane], s2 = sBHH[128+lane];
    float d0 = sBHH[lane], d1 = sBHH[64+lane], d2 = sBHH[128+lane];
    const float4* wiA = (const float4*)(Wih + (size_t)lane*MEM);
    const float4* wiB = (const float4*)(Wih + (size_t)(64+lane)*MEM);
    const float4* wiC = (const float4*)(Wih + (size_t)(128+lane)*MEM);
    const float4* whA = (const float4*)(Whh + (size_t)lane*MEM);
    const float4* whB = (const float4*)(Whh + (size_t)(64+lane)*MEM);
    const float4* whC = (const float4*)(Whh + (size_t)(128+lane)*MEM);
    const float4* M4 = (const float4*)(X + 192);
    const float4* XS = (const float4*)(X);
    const float4* XD = (const float4*)(X + 64);
    #pragma unroll
    for (int kc = 0; kc < 16; kc++) {
      float4 m = M4[kc], xs = XS[kc], xd = XD[kc];
      float4 a = wiA[kc], b = wiB[kc], c = wiC[kc];
      gi0 += a.x*m.x; gi0 += a.y*m.y; gi0 += a.z*m.z; gi0 += a.w*m.w;
      gi1 += b.x*m.x; gi1 += b.y*m.y; gi1 += b.z*m.z; gi1 += b.w*m.w;
      gi2 += c.x*m.x; gi2 += c.y*m.y; gi2 += c.z*m.z; gi2 += c.w*m.w;
      float4 p = whA[kc], q = whB[kc], r4 = whC[kc];
      s0 += p.x*xs.x; s0 += p.y*xs.y; s0 += p.z*xs.z; s0 += p.w*xs.w;
      s1 += q.x*xs.x; s1 += q.y*xs.y; s1 += q.z*xs.z; s1 += q.w*xs.w;
      s2 += r4.x*xs.x; s2 += r4.y*xs.y; s2 += r4.z*xs.z; s2 += r4.w*xs.w;
      d0 += p.x*xd.x; d0 += p.y*xd.y; d0 += p.z*xd.z; d0 += p.w*xd.w;
      d1 += q.x*xd.x; d1 += q.y*xd.y; d1 += q.z*xd.z; d1 += q.w*xd.w;
      d2 += r4.x*xd.x; d2 += r4.y*xd.y; d2 += r4.z*xd.z; d2 += r4.w*xd.w;
    }
    float hs = X[lane], hd = X[64+lane];
    float r = sigmoidf_(gi0 + s0);
    float z = sigmoidf_(gi1 + s1);
    float n = tanhf(gi2 + r*s2);
    float hns = (1.f - z)*n + z*hs;
    if (!same) {
      float r2 = sigmoidf_(gi0 + d0);
      float z2 = sigmoidf_(gi1 + d1);
      float n2 = tanhf(gi2 + r2*d2);
      float hnd = (1.f - z2)*n2 + z2*hd;
      sHf[ss*64 + lane] = hns;
      sHf[dd*64 + lane] = hnd;
    } else {
      sHf[ss*64 + lane] = hns;
    }
  }
  __syncthreads();
  // D: same-node second GRU on updated h (reference semantics)
  if (act && same) {
    float g0 = sBHH[lane], g1 = sBHH[64+lane], g2 = sBHH[128+lane];
    const float4* whA = (const float4*)(Whh + (size_t)lane*MEM);
    const float4* whB = (const float4*)(Whh + (size_t)(64+lane)*MEM);
    const float4* whC = (const float4*)(Whh + (size_t)(128+lane)*MEM);
    const float4* HP = (const float4*)(sHf + ss*64);
    #pragma unroll
    for (int kc = 0; kc < 16; kc++) {
      float4 hp = HP[kc], p = whA[kc], q = whB[kc], r4 = whC[kc];
      g0 += p.x*hp.x; g0 += p.y*hp.y; g0 += p.z*hp.z; g0 += p.w*hp.w;
      g1 += q.x*hp.x; g1 += q.y*hp.y; g1 += q.z*hp.z; g1 += q.w*hp.w;
      g2 += r4.x*hp.x; g2 += r4.y*hp.y; g2 += r4.z*hp.z; g2 += r4.w*hp.w;
    }
    float hpl = sHf[ss*64 + lane];
    float r = sigmoidf_(gi0 + g0);
    float z = sigmoidf_(gi1 + g1);
    float n = tanhf(gi2 + r*g2);
    sHf[ss*64 + lane] = (1.f - z)*n + z*hpl;
  }
  __syncthreads();
}

__global__ __launch_bounds__(1024, 1) void k_all(
    const float* __restrict__ nf, const int* __restrict__ src, const int* __restrict__ dst,
    const float* __restrict__ ts, const float* __restrict__ ef,
    const float* __restrict__ Wnp, const float* __restrict__ bnp,
    const float* __restrict__ Wmsg, const float* __restrict__ bmsg,
    const float* __restrict__ Wih, const float* __restrict__ Whh,
    const float* __restrict__ bih, const float* __restrict__ bhh,
    const float* __restrict__ w0, const float* __restrict__ b0,
    const float* __restrict__ tW, const float* __restrict__ tB,
    const float* __restrict__ Wg, const float* __restrict__ bg,
    const float* __restrict__ Wp, const float* __restrict__ bp,
    double* __restrict__ partials, int* __restrict__ wflag, float* __restrict__ out)
{
  __shared__ __align__(16) float smem[SMEM_F];
  int t = threadIdx.x, lane = t & 63, wv = t >> 6;
  int bid = blockIdx.x;

  if (bid > 0) {
    // ---------------- bulk block: 1024-row tile ----------------
    int b = bid - 1;
    long base = (long)b*ROWS_PB;
    int nrows = (int)min((long)ROWS_PB, (long)N_NODES - base);
    int nf4 = (nrows*NFEAT) >> 2;
    const float4* s4 = (const float4*)(nf + base*NFEAT);
    float4* tile4 = (float4*)smem;
    for (int i = t; i < nf4; i += 1024) tile4[i] = s4[i];
    float* sG  = smem + OFF_NF;       // 11
    float* sCl = smem + OFF_NF + 16;  // 1
    float* sW  = smem + OFF_NF + 32;  // [16][12]
    if (t < NFEAT) {
      float a = 0.f;
      #pragma unroll
      for (int j = 0; j < MEM; j++) a += Wnp[t*MEM+j]*Wg[j];
      sG[t] = a;
    }
    if (t == NFEAT) {
      float a = bg[0];
      #pragma unroll
      for (int j = 0; j < MEM; j++) a += bnp[j]*Wg[j];
      sCl[0] = a;
    }
    __syncthreads();
    float accE = 0.f, accS[NFEAT];
    #pragma unroll
    for (int k = 0; k < NFEAT; k++) accS[k] = 0.f;
    if (t < nrows) {
      float x[NFEAT];
      #pragma unroll
      for (int k = 0; k < NFEAT; k++) x[k] = smem[t*NFEAT + k];
      float l = sCl[0];
      #pragma unroll
      for (int k = 0; k < NFEAT; k++) l += x[k]*sG[k];
      float e = expf(l);
      accE = e;
      #pragma unroll
      for (int k = 0; k < NFEAT; k++) accS[k] = e*x[k];
    }
    #pragma unroll
    for (int off = 32; off; off >>= 1) {
      accE += __shfl_down(accE, off);
      #pragma unroll
      for (int k = 0; k < NFEAT; k++) accS[k] += __shfl_down(accS[k], off);
    }
    if (lane == 0) { sW[wv*12] = accE; for (int k = 0; k < NFEAT; k++) sW[wv*12+1+k] = accS[k]; }
    __syncthreads();
    if (t < 12) {
      double d = 0.0;
      #pragma unroll
      for (int w = 0; w < 16; w++) d += (double)sW[w*12 + t];
      partials[b*12 + t] = d;
    }
    __syncthreads();
    if (t == 0) {
      __threadfence();
      __hip_atomic_store(&wflag[bid], WF_MAGIC | bid, __ATOMIC_RELAXED, __HIP_MEMORY_SCOPE_AGENT);
    }
    return;
  }

  // ================= super-block: all 64 edges + readout + combine =================
  float* sHf   = smem + OFF_H;
  float* slab  = smem + OFF_SLAB;
  float* sNFf  = smem + OFF_NF;
  float* sWNP  = smem + OFF_WNP;
  float* sBIH  = smem + OFF_BIH;
  float* sBHH  = smem + OFF_BHH;
  float* sBMSG = smem + OFF_BMSG;
  float* sWGf  = smem + OFF_WG;
  float* sBNPf = smem + OFF_BNP;
  int* sEp  = (int*)(smem + OFF_INT);
  int* sMap = sEp + 128;
  int* sDef = sMap + 128;
  int* sAny = sDef + 64;

  // P0: stage small tensors
  if (t < 64) sEp[t] = src[t];
  else if (t < 128) sEp[t] = dst[t-64];
  if (t >= 128 && t < 192) { int j = t-128; sWGf[j] = Wg[j]; sBNPf[j] = bnp[j]; sBMSG[j] = bmsg[j]; }
  if (t >= 192 && t < 384) sBIH[t-192] = bih[t-192];
  if (t >= 384 && t < 576) sBHH[t-384] = bhh[t-384];
  if (t < 176) ((float4*)sWNP)[t] = ((const float4*)Wnp)[t];
  __syncthreads();
  // P1: canonical map + nf rows
  if (t < 128) {
    int id = sEp[t]; int fo = t;
    for (int i = 0; i < 128; i++) if (sEp[i] == id) { fo = i; break; }
    sMap[t] = fo;
  }
  for (int i = t; i < NSLOT*NFEAT; i += 1024) {
    int s = i / NFEAT, k = i - s*NFEAT;
    sNFf[s*12 + k] = nf[(long)sEp[s]*NFEAT + k];
  }
  __syncthreads();
  // P2: init sH = nf@Wnp + bnp for all slots; deferral via wave-0 ballot relaxation
  for (int p = t; p < NSLOT*MEM; p += 1024) {
    int i = p >> 6, j = p & 63;
    float a = sBNPf[j];
    #pragma unroll
    for (int k = 0; k < NFEAT; k++) a += sNFf[i*12 + k]*sWNP[k*64 + j];
    sHf[p] = a;
  }
  if (wv == 0) {
    int e = lane, ss = sMap[e], dd = sMap[64+e];
    unsigned long long cm = 0ull, st = 0ull;
    for (int y = 0; y < e; y++) {
      bool c = (sMap[y]==ss) || (sMap[y]==dd) || (sMap[64+y]==ss) || (sMap[64+y]==dd);
      if (c) { cm |= 1ull << y; if ((y >> 4) == (e >> 4)) st |= 1ull << y; }
    }
    bool def = false;
    for (int it = 0; it < 64; ++it) {
      unsigned long long dm = __ballot(def);
      def = ((cm & st) != 0ull) || ((cm & dm) != 0ull);
    }
    sDef[e] = def ? 1 : 0;
  }
  __syncthreads();
  if (t == 0) { int a = 0; for (int e = 0; e < 64; e++) a |= sDef[e]; sAny[0] = a; }
  __syncthreads();

  // ticks: 16 edges in parallel (1 wave each), 4 ticks
  for (int tick = 0; tick < 4; ++tick) {
    int e = tick*16 + wv;
    bool act = (sDef[e] == 0);
    edge_phases(e, act, wv, lane, sHf, slab, sMap, sBIH, sBHH, sBMSG,
                Wmsg, Wih, Whh, ef, ts, w0, b0, tW, tB);
  }
  // deferred (conflicting) edges: strict edge order, wave 0 only — rare
  if (sAny[0]) {
    for (int e = 0; e < 64; e++) {
      if (sDef[e]) {
        edge_phases(e, wv == 0, 0, lane, sHf, slab, sMap, sBIH, sBHH, sBMSG,
                    Wmsg, Wih, Whh, ef, ts, w0, b0, tW, tB);
      }
    }
  }

  // ---------------- readout (states in LDS) ----------------
  double* dA   = (double*)slab;       // [16][12]
  double* dTot = dA + 192;            // 12
  double* dScal= dTot + 12;           // 2
  double* dM   = dScal + 2;           // 64
  float*  fE0  = (float*)(dM + 64);   // 16
  float*  fE1  = fE0 + 16;            // 16
  float*  fS0  = fE1 + 16;            // [16][11]
  float*  fQ   = fS0 + 176;           // [16][64]
  float bg0 = bg[0];
  {
    float accE0 = 0.f, accE1 = 0.f, accQ = 0.f, accS0[NFEAT];
    #pragma unroll
    for (int k = 0; k < NFEAT; k++) accS0[k] = 0.f;
    #pragma unroll
    for (int it = 0; it < 8; ++it) {
      int s = it*16 + wv;
      bool used = (sMap[s] == s);
      float h = sHf[s*64 + lane];
      float h0 = sBNPf[lane];
      #pragma unroll
      for (int k = 0; k < NFEAT; k++) h0 += sNFf[s*12 + k]*sWNP[k*64 + lane];
      float v0 = h0 * sWGf[lane];
      float v1 = h * sWGf[lane];
      #pragma unroll
      for (int off = 32; off; off >>= 1) { v0 += __shfl_xor(v0, off); v1 += __shfl_xor(v1, off); }
      float e0 = used ? expf(v0 + bg0) : 0.f;
      float e1 = used ? expf(v1 + bg0) : 0.f;
      accE0 += e0; accE1 += e1;
      #pragma unroll
      for (int k = 0; k < NFEAT; k++) accS0[k] += e0*sNFf[s*12 + k];
      accQ += e1 * h;
    }
    if (lane == 0) { fE0[wv] = accE0; fE1[wv] = accE1; for (int k = 0; k < NFEAT; k++) fS0[wv*11 + k] = accS0[k]; }
    fQ[wv*64 + lane] = accQ;
  }
  // quiet poll for bulk flags (bulk finished long ago)
  if (t < NB_BULK) {
    int want = WF_MAGIC | (1 + t);
    while (__hip_atomic_load(&wflag[1 + t], __ATOMIC_RELAXED, __HIP_MEMORY_SCOPE_AGENT) != want)
      __builtin_amdgcn_s_sleep(8);
  }
  __threadfence();
  __syncthreads();

  double v[12];
  #pragma unroll
  for (int k = 0; k < 12; k++) v[k] = (t < NB_BULK) ? partials[t*12 + k] : 0.0;
  #pragma unroll
  for (int off = 32; off; off >>= 1) {
    #pragma unroll
    for (int k = 0; k < 12; k++) v[k] += __shfl_down(v[k], off);
  }
  if (lane == 0) { for (int k = 0; k < 12; k++) dA[wv*12 + k] = v[k]; }
  __syncthreads();
  if (t < 12) {
    double d = 0.0;
    #pragma unroll
    for (int w = 0; w < 16; w++) d += dA[w*12 + t];
    dTot[t] = d;
  }
  if (t == 12) { double d = 0.0; for (int w = 0; w < 16; w++) d += (double)fE0[w]; dScal[0] = d; }
  if (t == 13) { double d = 0.0; for (int w = 0; w < 16; w++) d += (double)fE1[w]; dScal[1] = d; }
  __syncthreads();
  if (t < MEM) {
    double Eall = dTot[0] - dScal[0];
    double a = Eall * (double)sBNPf[t];
    #pragma unroll
    for (int k = 0; k < NFEAT; k++) {
      double S0k = 0.0;
      #pragma unroll
      for (int w = 0; w < 16; w++) S0k += (double)fS0[w*11 + k];
      a += (dTot[1+k] - S0k) * (double)sWNP[k*64 + t];
    }
    double q = 0.0;
    #pragma unroll
    for (int w = 0; w < 16; w++) q += (double)fQ[w*64 + t];
    dM[t] = a + q;
  }
  __syncthreads();
  if (t < MEM) {
    double Eall = dTot[0] - dScal[0];
    double den = Eall + dScal[1];
    double a = 0.0;
    #pragma unroll
    for (int m = 0; m < MEM; m++) a += dM[m] * (double)Wp[m*MEM + t];
    out[t] = (float)(a/den + (double)bp[t]);
  }
  // reset flags for next replay (0 != MAGIC|b; poison != MAGIC|b)
  if (t >= 1 && t <= NB_BULK) wflag[t] = 0;
}

extern "C" void kernel_launch(void* const* d_in, const int* in_sizes, int n_in,
                              void* d_out, int out_size, void* d_ws, size_t ws_size,
                              hipStream_t stream) {
  (void)in_sizes; (void)n_in; (void)out_size; (void)ws_size;
  const float* nf   = (const float*)d_in[0];
  const int*   src  = (const int*)d_in[1];
  const int*   dst  = (const int*)d_in[2];
  const float* ts   = (const float*)d_in[3];
  const float* ef   = (const float*)d_in[4];
  const float* Wnp  = (const float*)d_in[5];
  const float* bnp  = (const float*)d_in[6];
  const float* Wmsg = (const float*)d_in[7];
  const float* bmsg = (const float*)d_in[8];
  const float* Wih  = (const float*)d_in[9];
  const float* Whh  = (const float*)d_in[10];
  const float* bih  = (const float*)d_in[11];
  const float* bhh  = (const float*)d_in[12];
  const float* w0   = (const float*)d_in[13];
  const float* b0   = (const float*)d_in[14];
  const float* tW   = (const float*)d_in[15];
  const float* tB   = (const float*)d_in[16];
  const float* Wg   = (const float*)d_in[17];
  const float* bg   = (const float*)d_in[18];
  const float* Wp   = (const float*)d_in[19];
  const float* bp   = (const float*)d_in[20];

  double* partials = (double*)((char*)d_ws + WS_PART_OFF);
  int*    wflag    = (int*)((char*)d_ws + WS_WFLAG_OFF);
  float*  out      = (float*)d_out;

  k_all<<<GRID_ALL, 1024, 0, stream>>>(
      nf, src, dst, ts, ef, Wnp, bnp, Wmsg, bmsg,
      Wih, Whh, bih, bhh, w0, b0, tW, tB, Wg, bg, Wp, bp,
      partials, wflag, out);
}

// Round 16
// 34.660 us; speedup vs baseline: 19.9475x; 19.9475x over previous
//
#include <hip/hip_runtime.h>
#include <math.h>

#define N_NODES 100000
#define NEDGE 64
#define NFEAT 11
#define EFEAT 30
#define MEM 64
#define TD 16
#define MSGIN 174
#define G3 192
#define ROWS_PB 1024
#define NB_BULK 98            // ceil(100000/1024)
#define NSLOT 128
#define DONE_MAGIC 0x5A17E000

// ws layout (bytes)
#define WS_PART_OFF   0
#define WS_STATES_OFF ((size_t)NB_BULK*12*sizeof(double))
#define WS_DONE_OFF   (WS_STATES_OFF + (size_t)NSLOT*MEM*sizeof(float))

__device__ __forceinline__ float sigmoidf_(float x) { return 1.f/(1.f+expf(-x)); }

// ================= k1: 64 edge blocks + 98 bulk blocks =================
__global__ __launch_bounds__(256) void k_main(
    const float* __restrict__ nf, const int* __restrict__ src, const int* __restrict__ dst,
    const float* __restrict__ ts, const float* __restrict__ ef,
    const float* __restrict__ Wnp, const float* __restrict__ bnp,
    const float* __restrict__ Wmsg, const float* __restrict__ bmsg,
    const float* __restrict__ Wih, const float* __restrict__ Whh,
    const float* __restrict__ bih, const float* __restrict__ bhh,
    const float* __restrict__ w0, const float* __restrict__ b0,
    const float* __restrict__ tW, const float* __restrict__ tB,
    const float* __restrict__ Wg, const float* __restrict__ bg,
    double* __restrict__ partials, float* __restrict__ states,
    int* __restrict__ done)
{
  int t = threadIdx.x;
  int bid = blockIdx.x;

  // ---------------- bulk blocks: 1024-row tile (4 x 256 rows), float4-staged ----------------
  if (bid >= NEDGE) {
    __shared__ float sG[NFEAT];
    __shared__ float sCl;
    __shared__ __align__(16) float sTile[ROWS_PB*NFEAT];   // 44 KB
    __shared__ float sW[4][12];
    int b = bid - NEDGE;
    long base = (long)b*ROWS_PB;
    int nrows = (int)min((long)ROWS_PB, (long)N_NODES - base);
    int nf4 = (nrows*NFEAT) >> 2;                          // rows multiple of 4 -> exact
    const float4* src4 = (const float4*)(nf + base*NFEAT);
    for (int i = t; i < nf4; i += 256) ((float4*)sTile)[i] = src4[i];
    if (t < NFEAT) {
      float a = 0.f;
      #pragma unroll
      for (int j=0;j<MEM;j++) a += Wnp[t*MEM+j]*Wg[j];
      sG[t] = a;
    }
    if (t == NFEAT) {
      float a = bg[0];
      #pragma unroll
      for (int j=0;j<MEM;j++) a += bnp[j]*Wg[j];
      sCl = a;
    }
    __syncthreads();
    float accE = 0.f, accS[NFEAT];
    #pragma unroll
    for (int k=0;k<NFEAT;k++) accS[k]=0.f;
    #pragma unroll
    for (int rr = 0; rr < 4; rr++) {
      int row = rr*256 + t;
      if (row < nrows) {
        float x[NFEAT];
        #pragma unroll
        for (int k=0;k<NFEAT;k++) x[k] = sTile[row*NFEAT + k];
        float l = sCl;
        #pragma unroll
        for (int k=0;k<NFEAT;k++) l += x[k]*sG[k];
        float e = expf(l);
        accE += e;
        #pragma unroll
        for (int k=0;k<NFEAT;k++) accS[k] += e*x[k];
      }
    }
    #pragma unroll
    for (int off=32; off; off>>=1) {
      accE += __shfl_down(accE, off);
      #pragma unroll
      for (int k=0;k<NFEAT;k++) accS[k] += __shfl_down(accS[k], off);
    }
    int wv = t>>6;
    if ((t&63)==0) { sW[wv][0]=accE; for (int k=0;k<NFEAT;k++) sW[wv][1+k]=accS[k]; }
    __syncthreads();
    if (t < 12) {
      double d = (double)sW[0][t] + (double)sW[1][t] + (double)sW[2][t] + (double)sW[3][t];
      partials[b*12 + t] = d;
    }
    return;
  }

  // ---------------- edge block (proven protocol; plain state stores, release-ordered) ----------------
  __shared__ int sEp[128], sMap[128], sFirst[128];
  __shared__ float sX[176];
  __shared__ float sMsg[MEM];
  __shared__ float sGi[G3], sGhs[G3], sGhd[G3];
  __shared__ float sNewS[MEM];

  int mj = t >> 2, mg = t & 3, mk0 = mg*44;
  float wreg[44];
  #pragma unroll
  for (int kk = 0; kk < 44; kk++) {
    int k = mk0 + kk;
    wreg[kk] = (k < MSGIN) ? Wmsg[k*MEM + mj] : 0.f;
  }

  if (t < 64) sEp[t] = src[t];
  else if (t < 128) sEp[t] = dst[t-64];
  __syncthreads();
  if (t < 128) {
    int id = sEp[t]; int fo = t; int fe = t & 63;
    for (int i = 0; i < 128; i++) {
      if (sEp[i] == id) { if (i < fo) fo = i; int ei = i & 63; if (ei < fe) fe = ei; }
    }
    sMap[t] = fo; sFirst[t] = fe;
  }
  __syncthreads();

  int e = bid;
  int ss = sMap[e], dd = sMap[64+e];

  if (t < e) {
    bool c = (sMap[t]==ss) || (sMap[t]==dd) || (sMap[64+t]==ss) || (sMap[64+t]==dd);
    if (c) {
      int want = DONE_MAGIC | t;
      while (__hip_atomic_load(&done[t], __ATOMIC_ACQUIRE, __HIP_MEMORY_SCOPE_AGENT) != want)
        __builtin_amdgcn_s_sleep(2);
    }
  }
  __syncthreads();

  bool initS = (sFirst[ss] == e);
  bool initD = (sFirst[dd] == e);
  if (t < 64) {
    float v;
    if (initS) {
      const float* row = nf + (long)sEp[ss]*NFEAT;
      v = bnp[t];
      #pragma unroll
      for (int k = 0; k < NFEAT; k++) v += row[k]*Wnp[k*MEM + t];
    } else {
      v = states[ss*MEM + t];      // plain load: ordered by acquire spin above
    }
    sX[t] = v;
  } else if (t < 128) {
    int j = t - 64; float v;
    if (initD) {
      const float* row = nf + (long)sEp[dd]*NFEAT;
      v = bnp[j];
      #pragma unroll
      for (int k = 0; k < NFEAT; k++) v += row[k]*Wnp[k*MEM + j];
    } else {
      v = states[dd*MEM + j];      // plain load
    }
    sX[t] = v;
  } else if (t < 158) {
    sX[t] = ef[e*EFEAT + (t-128)];
  } else if (t < 174) {
    int q = t - 158; float tt = ts[e];
    sX[t] = (q == 0) ? (tt*w0[0] + b0[0]) : sinf(tt*tW[q-1] + tB[q-1]);
  } else if (t < 176) sX[t] = 0.f;
  __syncthreads();

  {
    float a0=0.f,a1=0.f,a2=0.f,a3=0.f;
    #pragma unroll
    for (int kk=0; kk<44; kk+=4) {
      a0 += wreg[kk]  * sX[mk0+kk];
      a1 += wreg[kk+1]* sX[mk0+kk+1];
      a2 += wreg[kk+2]* sX[mk0+kk+2];
      a3 += wreg[kk+3]* sX[mk0+kk+3];
    }
    float a = (a0+a1)+(a2+a3);
    a += __shfl_xor(a,1);
    a += __shfl_xor(a,2);
    if (mg == 0) sMsg[mj] = fmaxf(a + bmsg[mj], 0.f);
  }
  __syncthreads();

  if (t < G3) {
    const float4* wi4 = (const float4*)(Wih + t*MEM);
    const float4* wh4 = (const float4*)(Whh + t*MEM);
    float a0=0.f,a1=0.f,a2=0.f,a3=0.f;
    float b0v=0.f,b1v=0.f,b2v=0.f,b3v=0.f;
    float c0=0.f,c1=0.f,c2=0.f,c3=0.f;
    #pragma unroll
    for (int k = 0; k < MEM; k += 4) {
      float4 vi = wi4[k>>2];
      float4 vh = wh4[k>>2];
      a0 += vi.x*sMsg[k];   a1 += vi.y*sMsg[k+1];   a2 += vi.z*sMsg[k+2];   a3 += vi.w*sMsg[k+3];
      b0v+= vh.x*sX[k];     b1v+= vh.y*sX[k+1];     b2v+= vh.z*sX[k+2];     b3v+= vh.w*sX[k+3];
      c0 += vh.x*sX[64+k];  c1 += vh.y*sX[64+k+1];  c2 += vh.z*sX[64+k+2];  c3 += vh.w*sX[64+k+3];
    }
    sGi[t]  = (a0+a1)+(a2+a3) + bih[t];
    sGhs[t] = (b0v+b1v)+(b2v+b3v) + bhh[t];
    sGhd[t] = (c0+c1)+(c2+c3) + bhh[t];
  }
  __syncthreads();

  if (ss != dd) {
    if (t < 128) {
      int j = t & 63;
      bool iss = t < 64;
      float h = sX[t];
      const float* gh = iss ? sGhs : sGhd;
      float r = sigmoidf_(sGi[j] + gh[j]);
      float z = sigmoidf_(sGi[64+j] + gh[64+j]);
      float n = tanhf(sGi[128+j] + r*gh[128+j]);
      float hn = (1.f - z)*n + z*h;
      int slot = iss ? ss : dd;
      states[slot*MEM + j] = hn;   // plain store: ordered by RELEASE flag below
    }
  } else {
    if (t < 64) {
      float h = sX[t];
      float r = sigmoidf_(sGi[t] + sGhs[t]);
      float z = sigmoidf_(sGi[64+t] + sGhs[64+t]);
      float n = tanhf(sGi[128+t] + r*sGhs[128+t]);
      sNewS[t] = (1.f - z)*n + z*h;
    }
    __syncthreads();
    if (t < G3) {
      const float4* wh4 = (const float4*)(Whh + t*MEM);
      float b0v=0.f,b1v=0.f,b2v=0.f,b3v=0.f;
      #pragma unroll
      for (int k = 0; k < MEM; k += 4) {
        float4 vh = wh4[k>>2];
        b0v += vh.x*sNewS[k];  b1v += vh.y*sNewS[k+1];
        b2v += vh.z*sNewS[k+2]; b3v += vh.w*sNewS[k+3];
      }
      sGhd[t] = (b0v+b1v)+(b2v+b3v) + bhh[t];
    }
    __syncthreads();
    if (t < 64) {
      float h = sNewS[t];
      float r = sigmoidf_(sGi[t] + sGhd[t]);
      float z = sigmoidf_(sGi[64+t] + sGhd[64+t]);
      float n = tanhf(sGi[128+t] + r*sGhd[128+t]);
      float hn = (1.f - z)*n + z*h;
      states[ss*MEM + t] = hn;     // plain store
    }
  }
  __syncthreads();
  if (t == 0) __hip_atomic_store(&done[e], DONE_MAGIC | e, __ATOMIC_RELEASE, __HIP_MEMORY_SCOPE_AGENT);
}

// ================= k2: SLIM readout + combine (1 block, 1024 thr) =================
__global__ __launch_bounds__(1024) void k_fin(
    const float* __restrict__ nf, const int* __restrict__ src, const int* __restrict__ dst,
    const float* __restrict__ Wnp, const float* __restrict__ bnp,
    const float* __restrict__ Wg, const float* __restrict__ bg,
    const float* __restrict__ Wp, const float* __restrict__ bp,
    const double* __restrict__ partials, const float* __restrict__ states,
    int* __restrict__ done, float* __restrict__ out)
{
  __shared__ __align__(16) float sWnp[NFEAT][MEM];
  __shared__ float sNF[NSLOT][12];
  __shared__ int sEp[NSLOT], sMap[NSLOT];
  __shared__ float sWg[MEM], sBnp[MEM];
  __shared__ float sE0[16], sE1[16], sS0[16][NFEAT], sQ[16][MEM];
  __shared__ double sA[16][12];
  __shared__ double sTot[12];
  __shared__ double sM[MEM];
  __shared__ double sScal[2];

  int t = threadIdx.x, lane = t & 63, wv = t >> 6;
  float bg0 = bg[0];

  if (t < 64) sEp[t] = src[t];
  else if (t < 128) sEp[t] = dst[t-64];
  if (t >= 128 && t < 192) { int j=t-128; sWg[j]=Wg[j]; sBnp[j]=bnp[j]; }
  if (t < 176) ((float4*)&sWnp[0][0])[t] = ((const float4*)Wnp)[t];
  double v[12];
  #pragma unroll
  for (int k=0;k<12;k++) v[k] = (t < NB_BULK) ? partials[t*12+k] : 0.0;
  __syncthreads();
  if (t < 128) {
    int id = sEp[t]; int fo = t;
    for (int i = 0; i < 128; i++) if (sEp[i] == id) { fo = i; break; }
    sMap[t] = fo;
  }
  for (int i = t; i < NSLOT*NFEAT; i += 1024) {
    int s = i / NFEAT, k = i - s*NFEAT;
    sNF[s][k] = nf[(long)sEp[s]*NFEAT + k];
  }
  #pragma unroll
  for (int off=32; off; off>>=1) {
    #pragma unroll
    for (int k=0;k<12;k++) v[k] += __shfl_down(v[k], off);
  }
  if (lane == 0) { for (int k=0;k<12;k++) sA[wv][k] = v[k]; }
  __syncthreads();

  {
    float accE0 = 0.f, accE1 = 0.f, accQ = 0.f, accS0[NFEAT];
    #pragma unroll
    for (int k=0;k<NFEAT;k++) accS0[k] = 0.f;
    #pragma unroll
    for (int it = 0; it < 8; it++) {
      int s = it*16 + wv;
      bool used = (sMap[s] == s);
      float h = states[s*MEM + lane];   // plain load (kernel boundary publishes)
      float h0 = sBnp[lane];
      #pragma unroll
      for (int k=0;k<NFEAT;k++) h0 += sNF[s][k]*sWnp[k][lane];
      float v0 = h0 * sWg[lane];
      float v1 = h * sWg[lane];
      #pragma unroll
      for (int off=32; off; off>>=1) { v0 += __shfl_xor(v0, off); v1 += __shfl_xor(v1, off); }
      float e0 = used ? expf(v0 + bg0) : 0.f;
      float e1 = used ? expf(v1 + bg0) : 0.f;
      accE0 += e0; accE1 += e1;
      #pragma unroll
      for (int k=0;k<NFEAT;k++) accS0[k] += e0*sNF[s][k];
      accQ += e1 * h;
    }
    if (lane == 0) { sE0[wv] = accE0; sE1[wv] = accE1; for (int k=0;k<NFEAT;k++) sS0[wv][k] = accS0[k]; }
    sQ[wv][lane] = accQ;
  }
  __syncthreads();

  if (t < 12) {
    double d = 0.0;
    #pragma unroll
    for (int w=0;w<16;w++) d += sA[w][t];
    sTot[t] = d;
  }
  if (t == 12) { double d=0.0; for (int w=0;w<16;w++) d += (double)sE0[w]; sScal[0] = d; }
  if (t == 13) { double d=0.0; for (int w=0;w<16;w++) d += (double)sE1[w]; sScal[1] = d; }
  __syncthreads();

  if (t < MEM) {
    double Eall = sTot[0] - sScal[0];
    double a = Eall * (double)sBnp[t];
    #pragma unroll
    for (int k=0;k<NFEAT;k++) {
      double S0k = 0.0;
      #pragma unroll
      for (int w=0;w<16;w++) S0k += (double)sS0[w][k];
      a += (sTot[1+k] - S0k) * (double)sWnp[k][t];
    }
    double q = 0.0;
    #pragma unroll
    for (int w=0;w<16;w++) q += (double)sQ[w][t];
    sM[t] = a + q;
  }
  __syncthreads();
  if (t < MEM) {
    double Eall = sTot[0] - sScal[0];
    double den = Eall + sScal[1];
    double a = 0.0;
    #pragma unroll
    for (int m=0;m<MEM;m++) a += sM[m] * (double)Wp[m*MEM + t];
    out[t] = (float)(a/den + (double)bp[t]);
  }
  if (t < NEDGE) done[t] = 0;
}

extern "C" void kernel_launch(void* const* d_in, const int* in_sizes, int n_in,
                              void* d_out, int out_size, void* d_ws, size_t ws_size,
                              hipStream_t stream) {
  (void)in_sizes; (void)n_in; (void)out_size; (void)ws_size;
  const float* nf   = (const float*)d_in[0];
  const int*   src  = (const int*)d_in[1];
  const int*   dst  = (const int*)d_in[2];
  const float* ts   = (const float*)d_in[3];
  const float* ef   = (const float*)d_in[4];
  const float* Wnp  = (const float*)d_in[5];
  const float* bnp  = (const float*)d_in[6];
  const float* Wmsg = (const float*)d_in[7];
  const float* bmsg = (const float*)d_in[8];
  const float* Wih  = (const float*)d_in[9];
  const float* Whh  = (const float*)d_in[10];
  const float* bih  = (const float*)d_in[11];
  const float* bhh  = (const float*)d_in[12];
  const float* w0   = (const float*)d_in[13];
  const float* b0   = (const float*)d_in[14];
  const float* tW   = (const float*)d_in[15];
  const float* tB   = (const float*)d_in[16];
  const float* Wg   = (const float*)d_in[17];
  const float* bg   = (const float*)d_in[18];
  const float* Wp   = (const float*)d_in[19];
  const float* bp   = (const float*)d_in[20];

  double* partials = (double*)((char*)d_ws + WS_PART_OFF);
  float*  states   = (float*)((char*)d_ws + WS_STATES_OFF);
  int*    done     = (int*)((char*)d_ws + WS_DONE_OFF);
  float*  out      = (float*)d_out;

  k_main<<<NEDGE + NB_BULK, 256, 0, stream>>>(
      nf, src, dst, ts, ef, Wnp, bnp, Wmsg, bmsg,
      Wih, Whh, bih, bhh, w0, b0, tW, tB, Wg, bg,
      partials, states, done);
  k_fin<<<1, 1024, 0, stream>>>(nf, src, dst, Wnp, bnp, Wg, bg, Wp, bp,
                                partials, states, done, out);
}